// Round 5
// baseline (187.750 us; speedup 1.0000x reference)
//
#include <hip/hip_runtime.h>

// Axial 7x7 attention, fused. N=512, GRID=7, Cq=64, Cv=512, B=3584.
// Round-5: attack the 75% idle-cycle gap (r4: occ 35%, VALUBusy 18%, all
// traffic clean at 2 blocks/CU). Geometry change only; phase semantics are
// identical to the passing round-4 kernel.
//  - grid 2048 = (n, c-quarter of 128). 4 blocks of an n -> same XCD (swizzle).
//  - chunk = 32 channels, double-buffered (issue c+1 before compute c, one
//    trailing barrier per chunk). 12.5KB/block in flight x4 blocks/CU.
//  - LDS = max(kT 6776, 4 v-tiles 6384) + P 833 = 7609 dw = 30.4KB
//    -> 4 blocks/CU (32 waves, the hw cap). VGPR: r4 measured 52 < 64 cap.
//  - v-tile [7][228]: PV read bank-slot (w-g+q) mod 8, <=2-way -> free.

#define NEGINF (-1e20f)

constexpr int QK_SLICE = 7 * 7 * 64;    // 3136 floats per n (q/k arrays)
constexpr int V_SLICE  = 7 * 512 * 7;   // 25088 floats per n (v arrays / out)

__device__ __forceinline__ void g2l4(const float* g, float* l) {
    __builtin_amdgcn_global_load_lds(
        (const __attribute__((address_space(1))) void*)g,
        (__attribute__((address_space(3))) void*)l, 4, 0, 0);
}

__global__ __launch_bounds__(512, 8) void fused_axial(
    const float* __restrict__ qH, const float* __restrict__ kH,
    const float* __restrict__ vH, const float* __restrict__ qW,
    const float* __restrict__ kW, const float* __restrict__ vW,
    float* __restrict__ out)
{
    // LDS (dwords): region R = sm[0..6775]:
    //   phase K/L: kTH = R+0 (3388, [a][j][c] strides 484/68), kTW = R+3388
    //   phase PV : S0A = R+0, S0B = R+1596, S1A = R+3192, S1B = R+4788
    //              (v-tiles [7][228], 1596 dw each; kT dead after logits)
    // P = sm+6776 (49 rows x stride 17, 833 dw). Total 7609 dw = 30436 B.
    __shared__ float sm[7609];
    float* R = sm;
    float* P = sm + 6776;

    const int bid  = blockIdx.x;
    const int work = (bid & 7) * 256 + (bid >> 3);   // bijective XCD swizzle
    const int n    = work >> 2;
    const int cq   = work & 3;                        // c-quarter
    const int c0base = cq * 128;
    const int t    = threadIdx.x;
    const int lane = t & 63;
    const int wv   = t >> 6;                          // wave 0..7

    const float* qHn = qH + n * QK_SLICE;
    const float* kHn = kH + n * QK_SLICE;
    const float* qWn = qW + n * QK_SLICE;
    const float* kWn = kW + n * QK_SLICE;
    const float* vHn = vH + n * V_SLICE;
    const float* vWn = vW + n * V_SLICE;
    float* outn = out + n * V_SLICE;

    // ---- Phase K: gather-stage kT[arr][a][j][c] (98 insts, 8 waves) ----
    #pragma unroll
    for (int u = 0; u < 13; ++u) {
        const int r = wv + 8 * u;
        if (u < 12 || r < 98) {
            const int arr = r >= 49;
            const int wj  = r - 49 * arr;
            const int a   = (wj * 37) >> 8;           // wj/7
            const int j   = wj - 7 * a;
            const float* src = (arr ? kWn : kHn) + a * 448 + lane * 7 + j;
            float* dst = R + arr * 3388 + a * 484 + j * 68;   // + lane*4 implicit
            g2l4(src, dst);
        }
    }
    __syncthreads();   // kT staged (barrier drains vmcnt)

    // ---- Phase L: logits. wave -> (arr,a) group, lane -> (b,j) ----
    {
        const int b = lane >> 3;
        const int j = lane & 7;
        auto logit_group = [&](int gi) {
            const int arr = gi >= 7;
            const int a   = gi - 7 * arr;
            if (b < 7 && j < 7) {
                const float* qrow = (arr ? qWn : qHn) + (a * 7 + b) * 64;
                const float* krow = R + arr * 3388 + a * 484 + j * 68;
                float e = 0.f;
                #pragma unroll
                for (int cc = 0; cc < 64; cc += 4) {
                    float4 qv = *(const float4*)(qrow + cc);
                    float4 kv = *(const float4*)(krow + cc);
                    e += qv.x * kv.x + qv.y * kv.y + qv.z * kv.z + qv.w * kv.w;
                }
                if (!arr) {
                    if (b == j) e = NEGINF;           // diagonal mask (h==j)
                    P[(b * 7 + a) * 17 + j] = e;      // logits[h=b, w=a, j]
                } else {
                    P[(a * 7 + b) * 17 + 7 + j] = e;  // logits[h=a, w=b, 7+y]
                }
            }
        };
        logit_group(wv);
        if (wv < 6) logit_group(wv + 8);
    }
    __syncthreads();   // logits in P; kT region dead -> v-tiles may overwrite

    // v-stage issuer: one 32-ch array tile, 28 insts (w2 0..6 x part 0..3,
    // part 3 is a half-wave). 64 consecutive dwords per inst (coalesced).
    auto issue_v = [&](float* dstb, const float* srcb, int c0) {
        const float* s0 = srcb + c0 * 7 + lane;
        #pragma unroll
        for (int u = 0; u < 4; ++u) {
            const int r = wv + 8 * u;                 // 0..31, need r<28
            if (r < 28 && ((r & 3) < 3 || lane < 32)) {
                const int w2   = r >> 2;
                const int part = r & 3;
                g2l4(s0 + w2 * 3584 + part * 64, dstb + w2 * 228 + part * 64);
            }
        }
    };

    float* S0A = R;
    float* S0B = R + 1596;
    float* S1A = R + 3192;
    float* S1B = R + 4788;

    // issue chunk 0 into set 0; it flies under the softmax
    issue_v(S0A, vHn, c0base);
    issue_v(S0B, vWn, c0base);

    // ---- Phase S: softmax over 14 per (h,w) ----
    if (t < 49) {
        float* row = P + t * 17;
        float l[14];
        float m = -3.4e38f;
        #pragma unroll
        for (int k = 0; k < 14; ++k) { l[k] = row[k]; m = fmaxf(m, l[k]); }
        float s = 0.f;
        #pragma unroll
        for (int k = 0; k < 14; ++k) { l[k] = __expf(l[k] - m); s += l[k]; }
        float inv = 1.f / s;
        #pragma unroll
        for (int k = 0; k < 14; ++k) row[k] = l[k] * inv;
    }
    __syncthreads();   // chunk 0 landed; P final

    // ---- Phase PV: 4 chunks x 32 channels, 2-deep pipeline ----
    const int g  = (t * 1339) >> 16;     // t/49; active g 0..7
    const int hw = t - g * 49;
    const int h  = (hw * 37) >> 8;
    const int w  = hw - 7 * h;
    const bool active = (t < 392);

    float pr[14];
    if (active) {
        #pragma unroll
        for (int k = 0; k < 14; ++k) pr[k] = P[hw * 17 + k];
    }

    for (int chunk = 0; chunk < 4; ++chunk) {
        float* As = (chunk & 1) ? S1A : S0A;
        float* Bs = (chunk & 1) ? S1B : S0B;

        if (chunk < 3) {   // issue next chunk into the other set (free by now)
            float* nA = (chunk & 1) ? S0A : S1A;
            float* nB = (chunk & 1) ? S0B : S1B;
            issue_v(nA, vHn, c0base + (chunk + 1) * 32);
            issue_v(nB, vWn, c0base + (chunk + 1) * 32);
        }

        if (active) {
            const float* rowA = As + w * 228 + g * 28;   // quad g: c_local 4g..4g+3
            const float* rowB = Bs + h * 228 + g * 28;
            float ac[4] = {0.f, 0.f, 0.f, 0.f};
            #pragma unroll
            for (int q = 0; q < 7; ++q) {
                float4 f = *(const float4*)(rowA + 4 * q);
                ac[(4 * q + 0) / 7] += pr[(4 * q + 0) % 7] * f.x;
                ac[(4 * q + 1) / 7] += pr[(4 * q + 1) % 7] * f.y;
                ac[(4 * q + 2) / 7] += pr[(4 * q + 2) % 7] * f.z;
                ac[(4 * q + 3) / 7] += pr[(4 * q + 3) % 7] * f.w;
            }
            #pragma unroll
            for (int q = 0; q < 7; ++q) {
                float4 f = *(const float4*)(rowB + 4 * q);
                ac[(4 * q + 0) / 7] += pr[7 + (4 * q + 0) % 7] * f.x;
                ac[(4 * q + 1) / 7] += pr[7 + (4 * q + 1) % 7] * f.y;
                ac[(4 * q + 2) / 7] += pr[7 + (4 * q + 2) % 7] * f.z;
                ac[(4 * q + 3) / 7] += pr[7 + (4 * q + 3) % 7] * f.w;
            }
            float* o = outn + (c0base + chunk * 32 + g * 4) * 49 + hw;
            o[0]   = ac[0];
            o[49]  = ac[1];
            o[98]  = ac[2];
            o[147] = ac[3];
        }
        if (chunk < 3) __syncthreads();   // drains next-chunk loads; frees set
    }
}

extern "C" void kernel_launch(void* const* d_in, const int* in_sizes, int n_in,
                              void* d_out, int out_size, void* d_ws, size_t ws_size,
                              hipStream_t stream) {
    const float* qH = (const float*)d_in[0];
    const float* kH = (const float*)d_in[1];
    const float* vH = (const float*)d_in[2];
    const float* qW = (const float*)d_in[3];
    const float* kW = (const float*)d_in[4];
    const float* vW = (const float*)d_in[5];
    float* out = (float*)d_out;
    fused_axial<<<2048, 512, 0, stream>>>(qH, kH, vH, qW, kW, vW, out);
}

// Round 6
// 177.927 us; speedup vs baseline: 1.0552x; 1.0552x over previous
//
#include <hip/hip_runtime.h>

// Axial 7x7 attention, fused. N=512, GRID=7, Cq=64, Cv=512, B=3584.
// Round-6 = round-4 geometry (best: 62.6us, clean traffic, prologue x1) with
// ONE change: __syncthreads() replaced by raw s_barrier + COUNTED s_waitcnt
// (T3/T4). __syncthreads drains vmcnt(0) -> r4 exposed ~full HBM latency at
// every chunk barrier (75% idle cycles). Counted waits keep the next chunk's
// global_load_lds batch in flight across barriers; latency never exposed
// after the prologue.
//  - vmcnt(12) = conservative per-wave floor of one A+B issue batch (waves
//    issue 12-14 insts; waiting <=12 always over-waits, never under-waits,
//    regardless of uniform-branch vs exec-mask codegen).
//  - r5 lesson: c-splitting duplicates the prologue (kT+logits+softmax,
//    ~3.9us VALU/n) and regresses; stay at grid 512, prologue x1.

#define NEGINF (-1e20f)

constexpr int QK_SLICE = 7 * 7 * 64;    // 3136 floats per n (q/k arrays)
constexpr int V_SLICE  = 7 * 512 * 7;   // 25088 floats per n (v arrays / out)

__device__ __forceinline__ void g2l4(const float* g, float* l) {
    __builtin_amdgcn_global_load_lds(
        (const __attribute__((address_space(1))) void*)g,
        (__attribute__((address_space(3))) void*)l, 4, 0, 0);
}
__device__ __forceinline__ void waitv12() {   // newest issue-batch stays in flight
    asm volatile("s_waitcnt vmcnt(12)" ::: "memory");
    __builtin_amdgcn_sched_barrier(0);
}
__device__ __forceinline__ void waitv0() {
    asm volatile("s_waitcnt vmcnt(0)" ::: "memory");
    __builtin_amdgcn_sched_barrier(0);
}
__device__ __forceinline__ void waitlgkm0() {
    asm volatile("s_waitcnt lgkmcnt(0)" ::: "memory");
    __builtin_amdgcn_sched_barrier(0);
}
__device__ __forceinline__ void bar() { __builtin_amdgcn_s_barrier(); }

__global__ __launch_bounds__(512, 4) void fused_axial(
    const float* __restrict__ qH, const float* __restrict__ kH,
    const float* __restrict__ vH, const float* __restrict__ qW,
    const float* __restrict__ kW, const float* __restrict__ vW,
    float* __restrict__ out)
{
    // LDS (dwords):
    //   A0: 0..3163        (v-tile, [7][452])
    //   B0: 3164..6327
    //   U1: 6328..13103    union: {A1 = U1, B1 = U1+3164}  OR  {kTH = U1 (3388,
    //       [a][j][c] strides 484/68), kTW = U1+3388} -- kT dies after logits
    //   P : 13104..13936   (49 rows x stride 17)
    // total 13937 dwords = 55748 B -> 2 blocks/CU (grid 512 = 2/CU anyway).
    __shared__ float sm[13937];
    float* A0 = sm;
    float* B0 = sm + 3164;
    float* U1 = sm + 6328;
    float* A1 = U1;
    float* B1 = U1 + 3164;
    float* P  = sm + 13104;

    const int n    = blockIdx.x;
    const int t    = threadIdx.x;
    const int lane = t & 63;
    const int wv   = t >> 6;                          // wave 0..7

    const float* qHn = qH + n * QK_SLICE;
    const float* kHn = kH + n * QK_SLICE;
    const float* qWn = qW + n * QK_SLICE;
    const float* kWn = kW + n * QK_SLICE;
    const float* vHn = vH + n * V_SLICE;
    const float* vWn = vW + n * V_SLICE;
    float* outn = out + n * V_SLICE;

    // v-stage issuer: 49 coalesced insts (w2 0..6 x part 0..6), 256B each;
    // per-wave instruction count 6 (waves 1-7) or 7 (wave 0).
    auto issue_v = [&](float* dstb, const float* srcb, int c0) {
        const float* s0 = srcb + c0 * 7 + lane;
        #pragma unroll
        for (int u = 0; u < 7; ++u) {
            const int r = wv + 8 * u;
            if (u < 6 || r < 49) {
                const int w2   = (r * 37) >> 8;       // r/7
                const int part = r - 7 * w2;
                g2l4(s0 + w2 * 3584 + part * 64, dstb + w2 * 452 + part * 64);
            }
        }
    };

    // ---- Phase K: gather-stage kT[arr][a][j][c] into U1 (98 insts) ----
    #pragma unroll
    for (int u = 0; u < 13; ++u) {
        const int r = wv + 8 * u;
        if (u < 12 || r < 98) {
            const int arr = r >= 49;
            const int wj  = r - 49 * arr;
            const int a   = (wj * 37) >> 8;           // wj/7
            const int j   = wj - 7 * a;
            const float* src = (arr ? kWn : kHn) + a * 448 + lane * 7 + j;
            float* dst = U1 + arr * 3388 + a * 484 + j * 68;  // + lane*4 implicit
            g2l4(src, dst);
        }
    }
    // issue v chunk 0 now; it flies through the entire logits phase
    issue_v(A0, vHn, 0);
    issue_v(B0, vWn, 0);
    waitv12();          // kT landed (kT older than A0/B0 batch); A0/B0 in flight
    bar();

    // ---- Phase L: logits. wave -> (arr,a) group, lane -> (b,j) ----
    {
        const int b = lane >> 3;
        const int j = lane & 7;
        auto logit_group = [&](int gi) {
            const int arr = gi >= 7;
            const int a   = gi - 7 * arr;
            if (b < 7 && j < 7) {
                const float* qrow = (arr ? qWn : qHn) + (a * 7 + b) * 64;
                const float* krow = U1 + arr * 3388 + a * 484 + j * 68;
                float e = 0.f;
                #pragma unroll
                for (int cc = 0; cc < 64; cc += 4) {
                    float4 qv = *(const float4*)(qrow + cc);
                    float4 kv = *(const float4*)(krow + cc);
                    e += qv.x * kv.x + qv.y * kv.y + qv.z * kv.z + qv.w * kv.w;
                }
                if (!arr) {
                    if (b == j) e = NEGINF;           // diagonal mask (h==j)
                    P[(b * 7 + a) * 17 + j] = e;      // logits[h=b, w=a, j]
                } else {
                    P[(a * 7 + b) * 17 + 7 + j] = e;  // logits[h=a, w=b, 7+y]
                }
            }
        };
        logit_group(wv);
        if (wv < 6) logit_group(wv + 8);
    }
    waitlgkm0();        // P writes + kT reads complete
    bar();              // kT region (U1) now dead -> safe to overwrite with A1/B1

    // issue v chunk 1; flies through softmax
    issue_v(A1, vHn, 64);
    issue_v(B1, vWn, 64);

    // ---- Phase S: softmax over 14 per (h,w) ----
    if (t < 49) {
        float* row = P + t * 17;
        float l[14];
        float m = -3.4e38f;
        #pragma unroll
        for (int k = 0; k < 14; ++k) { l[k] = row[k]; m = fmaxf(m, l[k]); }
        float s = 0.f;
        #pragma unroll
        for (int k = 0; k < 14; ++k) { l[k] = __expf(l[k] - m); s += l[k]; }
        float inv = 1.f / s;
        #pragma unroll
        for (int k = 0; k < 14; ++k) row[k] = l[k] * inv;
    }
    waitlgkm0();        // P final
    waitv12();          // chunk 0 landed; chunk 1 stays in flight
    bar();

    // ---- Phase PV: 8 chunks x 64 channels, counted-wait double buffer ----
    const int g  = (t * 1339) >> 16;     // t/49
    const int hw = t - g * 49;
    const int h  = (hw * 37) >> 8;
    const int w  = hw - 7 * h;
    const bool active = (t < 490);

    float pr[14];
    if (active) {
        #pragma unroll
        for (int k = 0; k < 14; ++k) pr[k] = P[hw * 17 + k];
    }

    for (int chunk = 0; chunk < 8; ++chunk) {
        float* As = (chunk & 1) ? A1 : A0;
        float* Bs = (chunk & 1) ? B1 : B0;
        const int c0 = chunk * 64;

        if (active) {
            const float* rowA = As + w * 452;
            const float* rowB = Bs + h * 452;
            #pragma unroll
            for (int it = 0; it < 2; ++it) {
                if (it == 0 || g < 6) {
                    const int quad = g + 10 * it;          // 0..15
                    const float* ra = rowA + quad * 28;
                    const float* rb = rowB + quad * 28;
                    float ac[4] = {0.f, 0.f, 0.f, 0.f};
                    #pragma unroll
                    for (int q = 0; q < 7; ++q) {
                        float4 f = *(const float4*)(ra + 4 * q);
                        ac[(4 * q + 0) / 7] += pr[(4 * q + 0) % 7] * f.x;
                        ac[(4 * q + 1) / 7] += pr[(4 * q + 1) % 7] * f.y;
                        ac[(4 * q + 2) / 7] += pr[(4 * q + 2) % 7] * f.z;
                        ac[(4 * q + 3) / 7] += pr[(4 * q + 3) % 7] * f.w;
                    }
                    #pragma unroll
                    for (int q = 0; q < 7; ++q) {
                        float4 f = *(const float4*)(rb + 4 * q);
                        ac[(4 * q + 0) / 7] += pr[7 + (4 * q + 0) % 7] * f.x;
                        ac[(4 * q + 1) / 7] += pr[7 + (4 * q + 1) % 7] * f.y;
                        ac[(4 * q + 2) / 7] += pr[7 + (4 * q + 2) % 7] * f.z;
                        ac[(4 * q + 3) / 7] += pr[7 + (4 * q + 3) % 7] * f.w;
                    }
                    float* o = outn + (c0 + quad * 4) * 49 + hw;
                    o[0]   = ac[0];
                    o[49]  = ac[1];
                    o[98]  = ac[2];
                    o[147] = ac[3];
                }
            }
        }
        if (chunk == 7) break;
        waitlgkm0();    // this wave's reads of As/Bs complete
        bar();          // ALL waves done reading set[cur] -> safe to overwrite
        if (chunk < 6) {
            issue_v(As, vHn, (chunk + 2) * 64);
            issue_v(Bs, vWn, (chunk + 2) * 64);
            waitv12();  // chunk+1 fully landed; chunk+2 batch stays in flight
        } else {
            waitv0();   // tail: drain chunk 7 (issued at chunk 5)
        }
        bar();          // every wave's chunk+1 data visible in LDS
    }
}

extern "C" void kernel_launch(void* const* d_in, const int* in_sizes, int n_in,
                              void* d_out, int out_size, void* d_ws, size_t ws_size,
                              hipStream_t stream) {
    const float* qH = (const float*)d_in[0];
    const float* kH = (const float*)d_in[1];
    const float* vH = (const float*)d_in[2];
    const float* qW = (const float*)d_in[3];
    const float* kW = (const float*)d_in[4];
    const float* vW = (const float*)d_in[5];
    float* out = (float*)d_out;
    fused_axial<<<512, 512, 0, stream>>>(qH, kH, vH, qW, kW, vW, out);
}